// Round 3
// baseline (788.361 us; speedup 1.0000x reference)
//
#include <hip/hip_runtime.h>
#include <cstdint>
#include <cstddef>

// VarAttention: B=4, N=96, P=64, C=1024, H=16, hd=64. tokens = 24576.
// Buffers are FP32 (reference dtype). Internal compute: bf16 MFMA, fp32 accum.
#define PPP  64
#define CC   1024

typedef __attribute__((ext_vector_type(8))) short short8;
typedef __attribute__((ext_vector_type(4))) float floatx4;
typedef __attribute__((ext_vector_type(4))) unsigned short ushort4v;

__device__ inline float bf2f(unsigned short u) {
  union { unsigned int i; float f; } v; v.i = ((unsigned int)u) << 16; return v.f;
}
__device__ inline unsigned short f2bf(float f) {
  union { float f; unsigned int i; } v; v.f = f;
  unsigned int x = v.i;
  unsigned int r = (x + 0x7fffu + ((x >> 16) & 1u)) >> 16;  // RNE
  return (unsigned short)r;
}

// global->LDS direct DMA, 16B/lane; LDS dest = wave-uniform base + lane*16.
#define GLD16(gp, lp)                                                          \
  __builtin_amdgcn_global_load_lds(                                            \
      (const __attribute__((address_space(1))) void*)(gp),                     \
      (__attribute__((address_space(3))) void*)(lp), 16, 0, 0)

// ---------------------------------------------------------------------------
// Convert+transpose: dst_bf16[c][r] = src_f32[r][c]. Grid (Cc/32, R/32), 256.
// ---------------------------------------------------------------------------
__global__ __launch_bounds__(256) void transpose_f32_bf16(
    const float* __restrict__ src, unsigned short* __restrict__ dst,
    int R, int Cc, int src_stride) {
  __shared__ unsigned short tile[32][33];
  int tc = blockIdx.x * 32, tr = blockIdx.y * 32;
  int tx = threadIdx.x & 31, ty = threadIdx.x >> 5;  // 32 x 8
  for (int yy = ty; yy < 32; yy += 8)
    tile[yy][tx] = f2bf(src[(size_t)(tr + yy) * src_stride + tc + tx]);
  __syncthreads();
  for (int yy = ty; yy < 32; yy += 8)
    dst[(size_t)(tc + yy) * R + tr + tx] = tile[tx][yy];
}

// ---------------------------------------------------------------------------
// Mean-pool over P: xm_bf16[bn][c] = (1/P) sum_p x_f32[bn*P + p][c]
// ---------------------------------------------------------------------------
__global__ __launch_bounds__(256) void meanpool_k(
    const float* __restrict__ x, unsigned short* __restrict__ xm) {
  int idx = blockIdx.x * 256 + threadIdx.x;  // over 384*1024
  int bn = idx >> 10, c = idx & 1023;
  const float* p = x + (size_t)bn * (PPP * CC) + c;
  float s = 0.f;
#pragma unroll 8
  for (int pp = 0; pp < PPP; ++pp) s += p[(size_t)pp * CC];
  xm[idx] = f2bf(s * (1.0f / PPP));
}

// ---------------------------------------------------------------------------
// MFMA bf16 GEMM, fp32 output: C_f32[M][N] = A_bf16[M][K] @ BT_bf16[N][K]^T
// (+ fp32 bias). 128x128 tile, BK=32, 4 waves, 4x4 MFMA per wave.
// Fragment layouts (m89/m91 verified): A[m=lane&15][k=quad*8+j];
// B[k][n=lane&15]; C/D col=lane&15, row=quad*4+reg.
// ---------------------------------------------------------------------------
__global__ __launch_bounds__(256) void gemm_bt_f32out(
    const unsigned short* __restrict__ A, const unsigned short* __restrict__ BT,
    float* __restrict__ Cout, const float* __restrict__ bias,
    int M, int N, int K) {
  __shared__ unsigned short As[128 * 32];
  __shared__ unsigned short Bs[128 * 32];

  const int rowBase = blockIdx.y * 128;
  const int colBase = blockIdx.x * 128;
  const int t = threadIdx.x;
  const int wave = t >> 6, lane = t & 63;
  const int qr = wave >> 1, qc = wave & 1;
  const int m16 = lane & 15, quad = lane >> 4;

  floatx4 acc[4][4];
#pragma unroll
  for (int i = 0; i < 4; ++i)
#pragma unroll
    for (int j = 0; j < 4; ++j) {
      acc[i][j][0] = 0.f; acc[i][j][1] = 0.f; acc[i][j][2] = 0.f; acc[i][j][3] = 0.f;
    }

  for (int k0 = 0; k0 < K; k0 += 32) {
    __syncthreads();
#pragma unroll
    for (int u = 0; u < 2; ++u) {
      int ch = (u * 4 + wave) * 64 + lane;      // 0..511
      int row = ch >> 2, c8 = (ch & 3) << 3;
      GLD16(&A [(size_t)(rowBase + row) * K + k0 + c8], &As[ch * 8]);
      GLD16(&BT[(size_t)(colBase + row) * K + k0 + c8], &Bs[ch * 8]);
    }
    __syncthreads();

    short8 af[4], bfr[4];
#pragma unroll
    for (int i = 0; i < 4; ++i)
      af[i] = *(const short8*)&As[(qr * 64 + i * 16 + m16) * 32 + quad * 8];
#pragma unroll
    for (int j = 0; j < 4; ++j)
      bfr[j] = *(const short8*)&Bs[(qc * 64 + j * 16 + m16) * 32 + quad * 8];
#pragma unroll
    for (int i = 0; i < 4; ++i)
#pragma unroll
      for (int j = 0; j < 4; ++j)
        acc[i][j] = __builtin_amdgcn_mfma_f32_16x16x32_bf16(af[i], bfr[j], acc[i][j], 0, 0, 0);
  }

  float bv[4];
#pragma unroll
  for (int j = 0; j < 4; ++j)
    bv[j] = bias ? bias[colBase + qc * 64 + j * 16 + m16] : 0.f;

#pragma unroll
  for (int i = 0; i < 4; ++i) {
    int row0 = rowBase + qr * 64 + i * 16 + quad * 4;
#pragma unroll
    for (int j = 0; j < 4; ++j) {
      int col = colBase + qc * 64 + j * 16 + m16;
#pragma unroll
      for (int r = 0; r < 4; ++r)
        Cout[(size_t)(row0 + r) * N + col] = acc[i][j][r] + bv[j];
    }
  }
}

// ---------------------------------------------------------------------------
// MFMA GEMM with FP32 A (converted to bf16 during staging), bf16 BT, bf16 out.
// Used for V = x @ Wv. Same tile/fragment structure as gemm_bt_f32out.
// ---------------------------------------------------------------------------
__global__ __launch_bounds__(256) void gemm_a32_bf16out(
    const float* __restrict__ A, const unsigned short* __restrict__ BT,
    unsigned short* __restrict__ Cout, int M, int N, int K) {
  __shared__ unsigned short As[128 * 32];
  __shared__ unsigned short Bs[128 * 32];

  const int rowBase = blockIdx.y * 128;
  const int colBase = blockIdx.x * 128;
  const int t = threadIdx.x;
  const int wave = t >> 6, lane = t & 63;
  const int qr = wave >> 1, qc = wave & 1;
  const int m16 = lane & 15, quad = lane >> 4;

  floatx4 acc[4][4];
#pragma unroll
  for (int i = 0; i < 4; ++i)
#pragma unroll
    for (int j = 0; j < 4; ++j) {
      acc[i][j][0] = 0.f; acc[i][j][1] = 0.f; acc[i][j][2] = 0.f; acc[i][j][3] = 0.f;
    }

  for (int k0 = 0; k0 < K; k0 += 32) {
    __syncthreads();
    // B: async 16B DMA (bf16 already)
#pragma unroll
    for (int u = 0; u < 2; ++u) {
      int ch = (u * 4 + wave) * 64 + lane;
      int row = ch >> 2, c8 = (ch & 3) << 3;
      GLD16(&BT[(size_t)(colBase + row) * K + k0 + c8], &Bs[ch * 8]);
    }
    // A: fp32 -> bf16 convert during staging (4 floats / thread / iter)
#pragma unroll
    for (int u = 0; u < 4; ++u) {
      int ch = u * 256 + t;                     // 0..1023, 4 floats each
      int row = ch >> 3, c4 = (ch & 7) << 2;
      float4 v = *(const float4*)&A[(size_t)(rowBase + row) * K + k0 + c4];
      ushort4v pk;
      pk.x = f2bf(v.x); pk.y = f2bf(v.y); pk.z = f2bf(v.z); pk.w = f2bf(v.w);
      *(ushort4v*)&As[row * 32 + c4] = pk;
    }
    __syncthreads();

    short8 af[4], bfr[4];
#pragma unroll
    for (int i = 0; i < 4; ++i)
      af[i] = *(const short8*)&As[(qr * 64 + i * 16 + m16) * 32 + quad * 8];
#pragma unroll
    for (int j = 0; j < 4; ++j)
      bfr[j] = *(const short8*)&Bs[(qc * 64 + j * 16 + m16) * 32 + quad * 8];
#pragma unroll
    for (int i = 0; i < 4; ++i)
#pragma unroll
      for (int j = 0; j < 4; ++j)
        acc[i][j] = __builtin_amdgcn_mfma_f32_16x16x32_bf16(af[i], bfr[j], acc[i][j], 0, 0, 0);
  }

#pragma unroll
  for (int i = 0; i < 4; ++i) {
    int row0 = rowBase + qr * 64 + i * 16 + quad * 4;
#pragma unroll
    for (int j = 0; j < 4; ++j) {
      int col = colBase + qc * 64 + j * 16 + m16;
#pragma unroll
      for (int r = 0; r < 4; ++r)
        Cout[(size_t)(row0 + r) * N + col] = f2bf(acc[i][j][r]);
    }
  }
}

// ---------------------------------------------------------------------------
// Per-(b,h) scores + softmax. qk (384 x 2048) fp32: [0,1024)=q, [1024,2048)=k.
// attn out: (B,H,96,96) bf16. Grid 64, block 128.
// ---------------------------------------------------------------------------
__global__ __launch_bounds__(128) void softmax_k(
    const float* __restrict__ qk, unsigned short* __restrict__ attn) {
  int bh = blockIdx.x;
  int b = bh >> 4, h = bh & 15;
  __shared__ float qs[96][64];
  __shared__ float ks[96][64];
  int t = threadIdx.x;
  for (int idx = t; idx < 96 * 64; idx += 128) {
    int n = idx >> 6, d = idx & 63;
    size_t rowoff = (size_t)(b * 96 + n) * 2048;
    qs[n][d] = qk[rowoff + h * 64 + d];
    ks[n][d] = qk[rowoff + 1024 + h * 64 + d];
  }
  __syncthreads();
  if (t < 96) {
    float sc[96];
    float mx = -1e30f;
    for (int m = 0; m < 96; ++m) {
      float s = 0.f;
#pragma unroll 16
      for (int d = 0; d < 64; ++d) s += qs[t][d] * ks[m][d];
      s *= 0.125f;  // hd^-0.5
      sc[m] = s;
      mx = fmaxf(mx, s);
    }
    float sum = 0.f;
    for (int m = 0; m < 96; ++m) { sc[m] = __expf(sc[m] - mx); sum += sc[m]; }
    float inv = 1.0f / sum;
    size_t base = (size_t)(bh * 96 + t) * 96;
    for (int m = 0; m < 96; ++m) attn[base + m] = f2bf(sc[m] * inv);
  }
}

// ---------------------------------------------------------------------------
// attn-apply for ONE batch b: out2[n,p,h*64+d] = sum_m attn_b[h,n,m]*Vb[m,p,h*64+d]
// Grid 1024 blocks (p,h), 256 threads. Vb/out2_b are (96*64 x 1024) bf16.
// ---------------------------------------------------------------------------
__global__ __launch_bounds__(256) void attn_apply_b(
    const unsigned short* __restrict__ attn_b, const unsigned short* __restrict__ Vb,
    unsigned short* __restrict__ out2_b) {
  int bid = blockIdx.x;
  int h = bid & 15, p = bid >> 4;
  __shared__ float at[96][96];   // 36 KB
  __shared__ float vs[96][64];   // 24 KB
  int t = threadIdx.x;
  size_t abase = (size_t)h * 96 * 96;
  for (int idx = t; idx < 96 * 96; idx += 256)
    at[idx / 96][idx % 96] = bf2f(attn_b[abase + idx]);
  for (int idx = t; idx < 96 * 64; idx += 256) {
    int m = idx >> 6, d = idx & 63;
    vs[m][d] = bf2f(Vb[(size_t)(m * 64 + p) * CC + h * 64 + d]);
  }
  __syncthreads();
  int d = t & 63, n0 = t >> 6;
  for (int n = n0; n < 96; n += 4) {
    float acc = 0.f;
#pragma unroll 16
    for (int m = 0; m < 96; ++m) acc += at[n][m] * vs[m][d];
    out2_b[(size_t)(n * 64 + p) * CC + h * 64 + d] = f2bf(acc);
  }
}

// ---------------------------------------------------------------------------
// Buffers (fp32 world):
//   d_out = 24576x1024 fp32 = 96 MB. Top half [48MB,96MB) temporarily holds
//   V (24576x1024 bf16 = 48 MB). Write-order proof for the b-chunked tail:
//   out chunk b writes fp32 bytes [24MB*b, 24MB*(b+1)); V[b'] lives at
//   [48+12b', 48+12(b'+1)) MB. Chunks 0,1 write [0,48) — disjoint from V.
//   Chunk 2 writes [48,72) — V[0],V[1] already consumed. Chunk 3 writes
//   [72,96) — apply_3 (reads V[3] at [84,96)) runs before gemm_3. Safe.
//   d_ws (24.9 MB): WqkvT 6MB | WpT 2MB | xm .75MB | qkbuf 3MB | attn 1.125MB
//   | out2 chunk 12MB.
// ---------------------------------------------------------------------------
extern "C" void kernel_launch(void* const* d_in, const int* in_sizes, int n_in,
                              void* d_out, int out_size, void* d_ws, size_t ws_size,
                              hipStream_t stream) {
  const float* x      = (const float*)d_in[0];  // (4,96,64,1024) fp32
  const float* W_qkv  = (const float*)d_in[1];  // (1024,3072) fp32
  const float* W_proj = (const float*)d_in[2];  // (1024,1024) fp32
  const float* b_proj = (const float*)d_in[3];  // (1024,) fp32
  float* out = (float*)d_out;                   // (4,96,64,1024) fp32

  char* w = (char*)d_ws;
  unsigned short* WqkvT = (unsigned short*)(w);                    // 6 MB
  unsigned short* WpT   = (unsigned short*)(w + 6291456);          // 2 MB
  unsigned short* xm    = (unsigned short*)(w + 8388608);          // 0.75 MB
  float*          qkbuf = (float*)(w + 9175040);                   // 3 MB
  unsigned short* attn  = (unsigned short*)(w + 12320768);         // 1.125 MB
  unsigned short* out2c = (unsigned short*)(w + 13500416);         // 12 MB
  unsigned short* Vbuf  = (unsigned short*)((char*)d_out + 50331648);  // 48 MB

  // 1) weight convert+transpose (B^T bf16 layout for the MFMA GEMM)
  transpose_f32_bf16<<<dim3(96, 32), 256, 0, stream>>>(W_qkv, WqkvT, 1024, 3072, 3072);
  transpose_f32_bf16<<<dim3(32, 32), 256, 0, stream>>>(W_proj, WpT, 1024, 1024, 1024);

  // 2) mean-pool x over P (q/k need only the pooled input — linearity)
  meanpool_k<<<dim3(384 * 1024 / 256), 256, 0, stream>>>(x, xm);

  // 3) qk = xm @ W_qkv[:, :2048] -> fp32
  gemm_bt_f32out<<<dim3(16, 3), 256, 0, stream>>>(
      xm, WqkvT, qkbuf, nullptr, 384, 2048, 1024);

  // 4) scores + softmax -> attn bf16
  softmax_k<<<dim3(64), 128, 0, stream>>>(qkbuf, attn);

  // 5) V = x @ W_qkv[:, 2048:3072] -> bf16, into top half of d_out
  gemm_a32_bf16out<<<dim3(8, 192), 256, 0, stream>>>(
      x, WqkvT + (size_t)2048 * 1024, Vbuf, 24576, 1024, 1024);

  // 6+7) per-batch: attn-mix then projection (+bias) -> fp32 out
  for (int b = 0; b < 4; ++b) {
    attn_apply_b<<<dim3(1024), 256, 0, stream>>>(
        attn + (size_t)b * 16 * 96 * 96,
        Vbuf + (size_t)b * 6144 * 1024,
        out2c);
    gemm_bt_f32out<<<dim3(8, 48), 256, 0, stream>>>(
        out2c, WpT, out + (size_t)b * 6144 * 1024, b_proj, 6144, 1024, 1024);
  }
}

// Round 4
// 677.095 us; speedup vs baseline: 1.1643x; 1.1643x over previous
//
#include <hip/hip_runtime.h>
#include <cstdint>
#include <cstddef>

// VarAttention: B=4, N=96, P=64, C=1024, H=16, hd=64. tokens = 24576.
// Buffers are FP32 (reference dtype). Internal compute: bf16 MFMA, fp32 accum.
#define PPP  64
#define CC   1024

typedef __attribute__((ext_vector_type(8))) short short8;
typedef __attribute__((ext_vector_type(4))) float floatx4;
typedef __attribute__((ext_vector_type(4))) unsigned short ushort4v;

__device__ inline float bf2f(unsigned short u) {
  union { unsigned int i; float f; } v; v.i = ((unsigned int)u) << 16; return v.f;
}
__device__ inline unsigned short f2bf(float f) {
  union { float f; unsigned int i; } v; v.f = f;
  unsigned int x = v.i;
  unsigned int r = (x + 0x7fffu + ((x >> 16) & 1u)) >> 16;  // RNE
  return (unsigned short)r;
}

// global->LDS direct DMA, 16B/lane; LDS dest = wave-uniform base + lane*16.
#define GLD16(gp, lp)                                                          \
  __builtin_amdgcn_global_load_lds(                                            \
      (const __attribute__((address_space(1))) void*)(gp),                     \
      (__attribute__((address_space(3))) void*)(lp), 16, 0, 0)

// ---------------------------------------------------------------------------
// Fused convert + mean-pool: one pass over x (96 MB fp32).
//   xbf[bn*P+p][c] = bf16(x[...]);  xm[bn][c] = bf16(mean_p x)
// Grid: 384 blocks (one per bn), 256 threads, 4 cols per thread (float4).
// ---------------------------------------------------------------------------
__global__ __launch_bounds__(256) void conv_mean(
    const float* __restrict__ x, unsigned short* __restrict__ xbf,
    unsigned short* __restrict__ xm) {
  int bn = blockIdx.x;
  int c4 = threadIdx.x * 4;
  const float* xp = x + (size_t)bn * (PPP * CC) + c4;
  unsigned short* xo = xbf + (size_t)bn * (PPP * CC) + c4;
  float4 s = {0.f, 0.f, 0.f, 0.f};
#pragma unroll 8
  for (int p = 0; p < PPP; ++p) {
    float4 v = *(const float4*)&xp[(size_t)p * CC];
    s.x += v.x; s.y += v.y; s.z += v.z; s.w += v.w;
    ushort4v pk;
    pk.x = f2bf(v.x); pk.y = f2bf(v.y); pk.z = f2bf(v.z); pk.w = f2bf(v.w);
    *(ushort4v*)&xo[(size_t)p * CC] = pk;
  }
  ushort4v pm;
  pm.x = f2bf(s.x * (1.0f / PPP)); pm.y = f2bf(s.y * (1.0f / PPP));
  pm.z = f2bf(s.z * (1.0f / PPP)); pm.w = f2bf(s.w * (1.0f / PPP));
  *(ushort4v*)&xm[(size_t)bn * CC + c4] = pm;
}

// ---------------------------------------------------------------------------
// Convert+transpose: dst_bf16[c][r] = src_f32[r][c]. Grid (Cc/32, R/32), 256.
// ---------------------------------------------------------------------------
__global__ __launch_bounds__(256) void transpose_f32_bf16(
    const float* __restrict__ src, unsigned short* __restrict__ dst,
    int R, int Cc, int src_stride) {
  __shared__ unsigned short tile[32][33];
  int tc = blockIdx.x * 32, tr = blockIdx.y * 32;
  int tx = threadIdx.x & 31, ty = threadIdx.x >> 5;  // 32 x 8
  for (int yy = ty; yy < 32; yy += 8)
    tile[yy][tx] = f2bf(src[(size_t)(tr + yy) * src_stride + tc + tx]);
  __syncthreads();
  for (int yy = ty; yy < 32; yy += 8)
    dst[(size_t)(tc + yy) * R + tr + tx] = tile[tx][yy];
}

// ---------------------------------------------------------------------------
// MFMA bf16 GEMM: C[M][N] = A_bf16[M][K] @ BT_bf16[N][K]^T (+ fp32 bias).
// 128x128 tile, BK=32, 4 waves, 4x4 MFMA per wave; GLD16 staging (m97).
// 1-D grid of nbx*nby blocks. SWIZ (requires nbx==8, nby%8==0): XCD-aware
// mapping — each XCD (bid&7) owns a contiguous band of row-tiles so its
// 4 MiB L2 gets x8 A-tile reuse across the column tiles.
// Fragment layouts (m89/m91 verified): A[m=lane&15][k=quad*8+j];
// B[k][n=lane&15]; C/D col=lane&15, row=quad*4+reg.
// ---------------------------------------------------------------------------
template <bool F32OUT, bool SWIZ>
__global__ __launch_bounds__(256) void gemm_bt(
    const unsigned short* __restrict__ A, const unsigned short* __restrict__ BT,
    void* __restrict__ Cout, const float* __restrict__ bias,
    int M, int N, int K, int nbx) {
  __shared__ unsigned short As[128 * 32];
  __shared__ unsigned short Bs[128 * 32];

  int bx, by;
  {
    int bid = blockIdx.x;
    if (SWIZ) {
      bx = (bid >> 3) & 7;
      by = (bid & 7) * (gridDim.x >> 6) + (bid >> 6);
    } else {
      bx = bid % nbx;
      by = bid / nbx;
    }
  }
  const int rowBase = by * 128;
  const int colBase = bx * 128;
  const int t = threadIdx.x;
  const int wave = t >> 6, lane = t & 63;
  const int qr = wave >> 1, qc = wave & 1;
  const int m16 = lane & 15, quad = lane >> 4;

  floatx4 acc[4][4];
#pragma unroll
  for (int i = 0; i < 4; ++i)
#pragma unroll
    for (int j = 0; j < 4; ++j) {
      acc[i][j][0] = 0.f; acc[i][j][1] = 0.f; acc[i][j][2] = 0.f; acc[i][j][3] = 0.f;
    }

  for (int k0 = 0; k0 < K; k0 += 32) {
    __syncthreads();
#pragma unroll
    for (int u = 0; u < 2; ++u) {
      int ch = (u * 4 + wave) * 64 + lane;      // 0..511
      int row = ch >> 2, c8 = (ch & 3) << 3;    // 16B chunks of a 32-wide k-row
      GLD16(&A [(size_t)(rowBase + row) * K + k0 + c8], &As[ch * 8]);
      GLD16(&BT[(size_t)(colBase + row) * K + k0 + c8], &Bs[ch * 8]);
    }
    __syncthreads();

    short8 af[4], bfr[4];
#pragma unroll
    for (int i = 0; i < 4; ++i)
      af[i] = *(const short8*)&As[(qr * 64 + i * 16 + m16) * 32 + quad * 8];
#pragma unroll
    for (int j = 0; j < 4; ++j)
      bfr[j] = *(const short8*)&Bs[(qc * 64 + j * 16 + m16) * 32 + quad * 8];
#pragma unroll
    for (int i = 0; i < 4; ++i)
#pragma unroll
      for (int j = 0; j < 4; ++j)
        acc[i][j] = __builtin_amdgcn_mfma_f32_16x16x32_bf16(af[i], bfr[j], acc[i][j], 0, 0, 0);
  }

  float bv[4];
#pragma unroll
  for (int j = 0; j < 4; ++j)
    bv[j] = bias ? bias[colBase + qc * 64 + j * 16 + m16] : 0.f;

#pragma unroll
  for (int i = 0; i < 4; ++i) {
    int row0 = rowBase + qr * 64 + i * 16 + quad * 4;
#pragma unroll
    for (int j = 0; j < 4; ++j) {
      int col = colBase + qc * 64 + j * 16 + m16;
#pragma unroll
      for (int r = 0; r < 4; ++r) {
        float f = acc[i][j][r] + bv[j];
        if (F32OUT)
          ((float*)Cout)[(size_t)(row0 + r) * N + col] = f;
        else
          ((unsigned short*)Cout)[(size_t)(row0 + r) * N + col] = f2bf(f);
      }
    }
  }
}

// ---------------------------------------------------------------------------
// Per-(b,h) scores + softmax. qk (384 x 2048) fp32: [0,1024)=q, [1024,2048)=k.
// attn out: (B,H,96,96) bf16. Grid 64, block 128.
// ---------------------------------------------------------------------------
__global__ __launch_bounds__(128) void softmax_k(
    const float* __restrict__ qk, unsigned short* __restrict__ attn) {
  int bh = blockIdx.x;
  int b = bh >> 4, h = bh & 15;
  __shared__ float qs[96][64];
  __shared__ float ks[96][64];
  int t = threadIdx.x;
  for (int idx = t; idx < 96 * 64; idx += 128) {
    int n = idx >> 6, d = idx & 63;
    size_t rowoff = (size_t)(b * 96 + n) * 2048;
    qs[n][d] = qk[rowoff + h * 64 + d];
    ks[n][d] = qk[rowoff + 1024 + h * 64 + d];
  }
  __syncthreads();
  if (t < 96) {
    float sc[96];
    float mx = -1e30f;
    for (int m = 0; m < 96; ++m) {
      float s = 0.f;
#pragma unroll 16
      for (int d = 0; d < 64; ++d) s += qs[t][d] * ks[m][d];
      s *= 0.125f;  // hd^-0.5
      sc[m] = s;
      mx = fmaxf(mx, s);
    }
    float sum = 0.f;
    for (int m = 0; m < 96; ++m) { sc[m] = __expf(sc[m] - mx); sum += sc[m]; }
    float inv = 1.0f / sum;
    size_t base = (size_t)(bh * 96 + t) * 96;
    for (int m = 0; m < 96; ++m) attn[base + m] = f2bf(sc[m] * inv);
  }
}

// ---------------------------------------------------------------------------
// attn-apply: out2[b,n,p,h*64+d] = sum_m attn[b,h,n,m] * V[b,m,p,h*64+d]
// Grid G blocks (b = bid>>10 when G=4096, or pre-offset pointers with G=1024),
// 256 threads.
// ---------------------------------------------------------------------------
__global__ __launch_bounds__(256) void attn_apply(
    const unsigned short* __restrict__ attn, const unsigned short* __restrict__ V,
    unsigned short* __restrict__ out2) {
  int bid = blockIdx.x;
  int h = bid & 15, p = (bid >> 4) & 63, b = bid >> 10;
  __shared__ float at[96][96];   // 36 KB
  __shared__ float vs[96][64];   // 24 KB
  int t = threadIdx.x;
  size_t abase = (size_t)((b * 16 + h) * 96) * 96;
  for (int idx = t; idx < 96 * 96; idx += 256)
    at[idx / 96][idx % 96] = bf2f(attn[abase + idx]);
  for (int idx = t; idx < 96 * 64; idx += 256) {
    int m = idx >> 6, d = idx & 63;
    vs[m][d] = bf2f(V[(size_t)((b * 96 + m) * 64 + p) * CC + h * 64 + d]);
  }
  __syncthreads();
  int d = t & 63, n0 = t >> 6;
  for (int n = n0; n < 96; n += 4) {
    float acc = 0.f;
#pragma unroll 16
    for (int m = 0; m < 96; ++m) acc += at[n][m] * vs[m][d];
    out2[(size_t)((b * 96 + n) * 64 + p) * CC + h * 64 + d] = f2bf(acc);
  }
}

// ---------------------------------------------------------------------------
// Buffer plan (fp32 world):
//   d_out (96 MB fp32): [0,48) holds xbf (bf16 x) until the V-GEMM consumes
//   it; [48,96) holds V (bf16) until attn_apply consumes it. The final proj
//   GEMM then overwrites all of d_out with fp32 output.
//   Chunked fallback ordering proof: out chunk b writes [24b, 24(b+1)) MB.
//   Chunks 0,1 overwrite xbf (dead after V-GEMM). Chunk 2 writes [48,72) =
//   V[0],V[1] (dead after apply_0/1). Chunk 3 writes [72,96); apply_3 (reads
//   V[3] at [84,96)) precedes gemm_3 on the stream. Safe.
//   d_ws: WqkvT 6 | WpT 2 | xm .75 | qkbuf 3 | attn 1.125 | out2 (48 full /
//   12 chunked) MB.
// ---------------------------------------------------------------------------
extern "C" void kernel_launch(void* const* d_in, const int* in_sizes, int n_in,
                              void* d_out, int out_size, void* d_ws, size_t ws_size,
                              hipStream_t stream) {
  const float* x      = (const float*)d_in[0];  // (4,96,64,1024) fp32
  const float* W_qkv  = (const float*)d_in[1];  // (1024,3072) fp32
  const float* W_proj = (const float*)d_in[2];  // (1024,1024) fp32
  const float* b_proj = (const float*)d_in[3];  // (1024,) fp32
  float* out = (float*)d_out;                   // (4,96,64,1024) fp32

  char* w = (char*)d_ws;
  unsigned short* WqkvT = (unsigned short*)(w);                    // 6 MB
  unsigned short* WpT   = (unsigned short*)(w + 6291456);          // 2 MB
  unsigned short* xm    = (unsigned short*)(w + 8388608);          // 0.75 MB
  float*          qkbuf = (float*)(w + 9175040);                   // 3 MB
  unsigned short* attn  = (unsigned short*)(w + 12320768);         // 1.125 MB
  unsigned short* out2w = (unsigned short*)(w + 13500416);         // 48 or 12 MB
  unsigned short* xbf   = (unsigned short*)d_out;                      // 48 MB
  unsigned short* Vbuf  = (unsigned short*)((char*)d_out + 50331648);  // 48 MB

  const bool fullws = ws_size >= (size_t)13500416 + 50331648;

  // 1) fused convert(x->bf16) + mean-pool over P (q/k only need the mean)
  conv_mean<<<dim3(384), 256, 0, stream>>>(x, xbf, xm);

  // 2) weight convert+transpose (B^T bf16 layout)
  transpose_f32_bf16<<<dim3(96, 32), 256, 0, stream>>>(W_qkv, WqkvT, 1024, 3072, 3072);
  transpose_f32_bf16<<<dim3(32, 32), 256, 0, stream>>>(W_proj, WpT, 1024, 1024, 1024);

  // 3) qk = xm @ W_qkv[:, :2048] -> fp32 (small; plain mapping)
  gemm_bt<true, false><<<dim3(48), 256, 0, stream>>>(
      xm, WqkvT, qkbuf, nullptr, 384, 2048, 1024, 16);

  // 4) scores + softmax -> attn bf16
  softmax_k<<<dim3(64), 128, 0, stream>>>(qkbuf, attn);

  // 5) V = xbf @ W_qkv[:, 2048:3072] -> bf16 into d_out[48,96) (swizzled)
  gemm_bt<false, true><<<dim3(1536), 256, 0, stream>>>(
      xbf, WqkvT + (size_t)2048 * 1024, Vbuf, nullptr, 24576, 1024, 1024, 8);

  if (fullws) {
    // 6) attn-mix, all batches in one launch
    attn_apply<<<dim3(4096), 256, 0, stream>>>(attn, Vbuf, out2w);
    // 7) out = out2 @ W_proj + b_proj -> fp32, one full-M launch
    gemm_bt<true, true><<<dim3(1536), 256, 0, stream>>>(
        out2w, WpT, out, b_proj, 24576, 1024, 1024, 8);
  } else {
    for (int b = 0; b < 4; ++b) {
      attn_apply<<<dim3(1024), 256, 0, stream>>>(
          attn + (size_t)b * 16 * 96 * 96,
          Vbuf + (size_t)b * 6144 * 1024,
          out2w);
      gemm_bt<true, true><<<dim3(384), 256, 0, stream>>>(
          out2w, WpT, out + (size_t)b * 6144 * 1024, b_proj, 6144, 1024, 1024, 8);
    }
  }
}

// Round 5
// 471.439 us; speedup vs baseline: 1.6722x; 1.4362x over previous
//
#include <hip/hip_runtime.h>
#include <cstdint>
#include <cstddef>

// VarAttention: B=4, N=96, P=64, C=1024, H=16, hd=64. tokens = 24576.
// Buffers are FP32 (reference dtype). Internal compute: bf16 MFMA, fp32 accum.
#define PPP  64
#define CC   1024

typedef __attribute__((ext_vector_type(8))) short short8;
typedef __attribute__((ext_vector_type(4))) float floatx4;
typedef __attribute__((ext_vector_type(4))) unsigned short ushort4v;

__device__ inline float bf2f(unsigned short u) {
  union { unsigned int i; float f; } v; v.i = ((unsigned int)u) << 16; return v.f;
}
__device__ inline unsigned short f2bf(float f) {
  union { float f; unsigned int i; } v; v.f = f;
  unsigned int x = v.i;
  unsigned int r = (x + 0x7fffu + ((x >> 16) & 1u)) >> 16;  // RNE
  return (unsigned short)r;
}

// global->LDS direct DMA, 16B/lane; LDS dest = wave-uniform base + lane*16.
#define GLD16(gp, lp)                                                          \
  __builtin_amdgcn_global_load_lds(                                            \
      (const __attribute__((address_space(1))) void*)(gp),                     \
      (__attribute__((address_space(3))) void*)(lp), 16, 0, 0)

// ---------------------------------------------------------------------------
// Fused convert + mean-pool: one pass over x (96 MB fp32).
//   xbf[bn*P+p][c] = bf16(x[...]);  xm[bn][c] = bf16(mean_p x)
// ---------------------------------------------------------------------------
__global__ __launch_bounds__(256) void conv_mean(
    const float* __restrict__ x, unsigned short* __restrict__ xbf,
    unsigned short* __restrict__ xm) {
  int bn = blockIdx.x;
  int c4 = threadIdx.x * 4;
  const float* xp = x + (size_t)bn * (PPP * CC) + c4;
  unsigned short* xo = xbf + (size_t)bn * (PPP * CC) + c4;
  float4 s = {0.f, 0.f, 0.f, 0.f};
#pragma unroll 8
  for (int p = 0; p < PPP; ++p) {
    float4 v = *(const float4*)&xp[(size_t)p * CC];
    s.x += v.x; s.y += v.y; s.z += v.z; s.w += v.w;
    ushort4v pk;
    pk.x = f2bf(v.x); pk.y = f2bf(v.y); pk.z = f2bf(v.z); pk.w = f2bf(v.w);
    *(ushort4v*)&xo[(size_t)p * CC] = pk;
  }
  ushort4v pm;
  pm.x = f2bf(s.x * (1.0f / PPP)); pm.y = f2bf(s.y * (1.0f / PPP));
  pm.z = f2bf(s.z * (1.0f / PPP)); pm.w = f2bf(s.w * (1.0f / PPP));
  *(ushort4v*)&xm[(size_t)bn * CC + c4] = pm;
}

// ---------------------------------------------------------------------------
// Convert+transpose: dst_bf16[c][r] = src_f32[r][c]. Grid (Cc/32, R/32), 256.
// ---------------------------------------------------------------------------
__global__ __launch_bounds__(256) void transpose_f32_bf16(
    const float* __restrict__ src, unsigned short* __restrict__ dst,
    int R, int Cc, int src_stride) {
  __shared__ unsigned short tile[32][33];
  int tc = blockIdx.x * 32, tr = blockIdx.y * 32;
  int tx = threadIdx.x & 31, ty = threadIdx.x >> 5;  // 32 x 8
  for (int yy = ty; yy < 32; yy += 8)
    tile[yy][tx] = f2bf(src[(size_t)(tr + yy) * src_stride + tc + tx]);
  __syncthreads();
  for (int yy = ty; yy < 32; yy += 8)
    dst[(size_t)(tc + yy) * R + tr + tx] = tile[tx][yy];
}

// ---------------------------------------------------------------------------
// MFMA bf16 GEMM: C[M][N] = A_bf16[M][K] @ BT_bf16[N][K]^T (+ fp32 bias).
// 128x128 tile, BK=32, 4 waves, 4x4 MFMA per wave; GLD16 staging (m97).
// SWIZ: XCD-aware mapping (requires nbx==8, grid%64==0) — each XCD (bid&7)
// owns a contiguous row-tile band for x8 A reuse in its private L2.
// Fragment layouts (m89/m91 verified): A[m=lane&15][k=quad*8+j];
// B[k][n=lane&15]; C/D col=lane&15, row=quad*4+reg.
// ---------------------------------------------------------------------------
template <bool F32OUT, bool SWIZ>
__global__ __launch_bounds__(256) void gemm_bt(
    const unsigned short* __restrict__ A, const unsigned short* __restrict__ BT,
    void* __restrict__ Cout, const float* __restrict__ bias,
    int M, int N, int K, int nbx) {
  __shared__ unsigned short As[128 * 32];
  __shared__ unsigned short Bs[128 * 32];

  int bx, by;
  {
    int bid = blockIdx.x;
    if (SWIZ) {
      bx = (bid >> 3) & 7;
      by = (bid & 7) * (gridDim.x >> 6) + (bid >> 6);
    } else {
      bx = bid % nbx;
      by = bid / nbx;
    }
  }
  const int rowBase = by * 128;
  const int colBase = bx * 128;
  const int t = threadIdx.x;
  const int wave = t >> 6, lane = t & 63;
  const int qr = wave >> 1, qc = wave & 1;
  const int m16 = lane & 15, quad = lane >> 4;

  floatx4 acc[4][4];
#pragma unroll
  for (int i = 0; i < 4; ++i)
#pragma unroll
    for (int j = 0; j < 4; ++j) {
      acc[i][j][0] = 0.f; acc[i][j][1] = 0.f; acc[i][j][2] = 0.f; acc[i][j][3] = 0.f;
    }

  for (int k0 = 0; k0 < K; k0 += 32) {
    __syncthreads();
#pragma unroll
    for (int u = 0; u < 2; ++u) {
      int ch = (u * 4 + wave) * 64 + lane;      // 0..511
      int row = ch >> 2, c8 = (ch & 3) << 3;    // 16B chunks of a 32-wide k-row
      GLD16(&A [(size_t)(rowBase + row) * K + k0 + c8], &As[ch * 8]);
      GLD16(&BT[(size_t)(colBase + row) * K + k0 + c8], &Bs[ch * 8]);
    }
    __syncthreads();

    short8 af[4], bfr[4];
#pragma unroll
    for (int i = 0; i < 4; ++i)
      af[i] = *(const short8*)&As[(qr * 64 + i * 16 + m16) * 32 + quad * 8];
#pragma unroll
    for (int j = 0; j < 4; ++j)
      bfr[j] = *(const short8*)&Bs[(qc * 64 + j * 16 + m16) * 32 + quad * 8];
#pragma unroll
    for (int i = 0; i < 4; ++i)
#pragma unroll
      for (int j = 0; j < 4; ++j)
        acc[i][j] = __builtin_amdgcn_mfma_f32_16x16x32_bf16(af[i], bfr[j], acc[i][j], 0, 0, 0);
  }

  float bv[4];
#pragma unroll
  for (int j = 0; j < 4; ++j)
    bv[j] = bias ? bias[colBase + qc * 64 + j * 16 + m16] : 0.f;

#pragma unroll
  for (int i = 0; i < 4; ++i) {
    int row0 = rowBase + qr * 64 + i * 16 + quad * 4;
#pragma unroll
    for (int j = 0; j < 4; ++j) {
      int col = colBase + qc * 64 + j * 16 + m16;
#pragma unroll
      for (int r = 0; r < 4; ++r) {
        float f = acc[i][j][r] + bv[j];
        if (F32OUT)
          ((float*)Cout)[(size_t)(row0 + r) * N + col] = f;
        else
          ((unsigned short*)Cout)[(size_t)(row0 + r) * N + col] = f2bf(f);
      }
    }
  }
}

// ---------------------------------------------------------------------------
// Per-(b,h) scores + softmax. qk (384 x 2048) fp32: [0,1024)=q, [1024,2048)=k.
// attn out: (B,H,96,96) bf16. Grid 64, block 128.
// ---------------------------------------------------------------------------
__global__ __launch_bounds__(128) void softmax_k(
    const float* __restrict__ qk, unsigned short* __restrict__ attn) {
  int bh = blockIdx.x;
  int b = bh >> 4, h = bh & 15;
  __shared__ float qs[96][64];
  __shared__ float ks[96][64];
  int t = threadIdx.x;
  for (int idx = t; idx < 96 * 64; idx += 128) {
    int n = idx >> 6, d = idx & 63;
    size_t rowoff = (size_t)(b * 96 + n) * 2048;
    qs[n][d] = qk[rowoff + h * 64 + d];
    ks[n][d] = qk[rowoff + 1024 + h * 64 + d];
  }
  __syncthreads();
  if (t < 96) {
    float sc[96];
    float mx = -1e30f;
    for (int m = 0; m < 96; ++m) {
      float s = 0.f;
#pragma unroll 16
      for (int d = 0; d < 64; ++d) s += qs[t][d] * ks[m][d];
      s *= 0.125f;  // hd^-0.5
      sc[m] = s;
      mx = fmaxf(mx, s);
    }
    float sum = 0.f;
    for (int m = 0; m < 96; ++m) { sc[m] = __expf(sc[m] - mx); sum += sc[m]; }
    float inv = 1.0f / sum;
    size_t base = (size_t)(bh * 96 + t) * 96;
    for (int m = 0; m < 96; ++m) attn[base + m] = f2bf(sc[m] * inv);
  }
}

// ---------------------------------------------------------------------------
// MFMA attn-apply (no LDS). Per (b,h): out2'(96 x 4096) = attn_bh(96x96) @
// V'_bh(96x4096), where V'[m][p*64+d] = V[((b*96+m)*64+p)*1024 + h*64+d].
// Grid = NBH*32 blocks (bh = bid>>5, 128-col tile ct = bid&31), 256 threads.
// Wave w covers cols [w*32, w*32+32) as 2 subtiles; 6 row-tiles of 16; K=96.
// A fragments: contiguous 16B loads from attn (L2-hot). B fragments: 8x
// global_load_ushort gathers at 64KB m-stride (each 128B V line read by
// exactly one block). C/D: col=lane&15 (pd), row=quad*4+reg (token n).
// ---------------------------------------------------------------------------
__global__ __launch_bounds__(256) void attn_apply_mfma(
    const unsigned short* __restrict__ attn, const unsigned short* __restrict__ V,
    unsigned short* __restrict__ out2) {
  const int bid = blockIdx.x;
  const int bh = bid >> 5, ct = bid & 31;
  const int b = bh >> 4;           // 0 when launched per-batch with grid 512
  const int t = threadIdx.x;
  const int wave = t >> 6, lane = t & 63;
  const int m16 = lane & 15, quad = lane >> 4;

  const unsigned short* An = attn + (size_t)bh * 96 * 96;   // attn[bh][n][m]
  const int vb = b * 96 * 64 * CC;                           // batch offset in V

  floatx4 acc[6][2];
#pragma unroll
  for (int i = 0; i < 6; ++i)
#pragma unroll
    for (int j = 0; j < 2; ++j) {
      acc[i][j][0] = 0.f; acc[i][j][1] = 0.f; acc[i][j][2] = 0.f; acc[i][j][3] = 0.f;
    }

  // col geometry per subtile jj: col = ct*128 + wave*32 + jj*16 + m16
  int p_[2], base_[2];
#pragma unroll
  for (int jj = 0; jj < 2; ++jj) {
    int colL = wave * 32 + jj * 16;              // 0..112, multiple of 16
    int p = ct * 2 + (colL >> 6);
    int d = (colL & 63) + m16;
    p_[jj] = p;
    base_[jj] = vb + p * CC + ((bh & 15) * 64) + d;   // + m*64*CC per k
  }

#pragma unroll
  for (int k0 = 0; k0 < 96; k0 += 32) {
    short8 af[6];
#pragma unroll
    for (int i = 0; i < 6; ++i)
      af[i] = *(const short8*)&An[(i * 16 + m16) * 96 + k0 + quad * 8];
#pragma unroll
    for (int jj = 0; jj < 2; ++jj) {
      short8 bfr;
#pragma unroll
      for (int j = 0; j < 8; ++j)
        bfr[j] = (short)V[(size_t)base_[jj] + (size_t)(k0 + quad * 8 + j) * (64 * CC)];
#pragma unroll
      for (int i = 0; i < 6; ++i)
        acc[i][jj] = __builtin_amdgcn_mfma_f32_16x16x32_bf16(af[i], bfr, acc[i][jj], 0, 0, 0);
    }
  }

  // out2[((b*96+n)*64+p)*1024 + h*64 + d], n = i*16 + quad*4 + r
#pragma unroll
  for (int jj = 0; jj < 2; ++jj) {
    int colL = wave * 32 + jj * 16;
    int d = (colL & 63) + m16;
    size_t obase = (size_t)(b * 96) * 64 * CC + (size_t)p_[jj] * CC + (bh & 15) * 64 + d;
#pragma unroll
    for (int i = 0; i < 6; ++i) {
#pragma unroll
      for (int r = 0; r < 4; ++r) {
        int n = i * 16 + quad * 4 + r;
        out2[obase + (size_t)n * (64 * CC)] = f2bf(acc[i][jj][r]);
      }
    }
  }
}

// ---------------------------------------------------------------------------
// Buffer plan (fp32 world):
//   d_out (96 MB fp32): [0,48) holds xbf (bf16 x) until the V-GEMM consumes
//   it; [48,96) holds V (bf16) until attn_apply consumes it. The final proj
//   GEMM then overwrites all of d_out with fp32 output.
//   Chunked fallback ordering proof: out chunk b writes [24b, 24(b+1)) MB.
//   Chunks 0,1 overwrite xbf (dead after V-GEMM). Chunk 2 writes [48,72) =
//   V[0],V[1] (dead after apply_0/1). Chunk 3 writes [72,96); apply_3 (reads
//   V[3] at [84,96)) precedes gemm_3 on the stream. Safe.
//   d_ws: WqkvT 6 | WpT 2 | xm .75 | qkbuf 3 | attn 1.125 | out2 (48 full /
//   12 chunked) MB.
// ---------------------------------------------------------------------------
extern "C" void kernel_launch(void* const* d_in, const int* in_sizes, int n_in,
                              void* d_out, int out_size, void* d_ws, size_t ws_size,
                              hipStream_t stream) {
  const float* x      = (const float*)d_in[0];  // (4,96,64,1024) fp32
  const float* W_qkv  = (const float*)d_in[1];  // (1024,3072) fp32
  const float* W_proj = (const float*)d_in[2];  // (1024,1024) fp32
  const float* b_proj = (const float*)d_in[3];  // (1024,) fp32
  float* out = (float*)d_out;                   // (4,96,64,1024) fp32

  char* w = (char*)d_ws;
  unsigned short* WqkvT = (unsigned short*)(w);                    // 6 MB
  unsigned short* WpT   = (unsigned short*)(w + 6291456);          // 2 MB
  unsigned short* xm    = (unsigned short*)(w + 8388608);          // 0.75 MB
  float*          qkbuf = (float*)(w + 9175040);                   // 3 MB
  unsigned short* attn  = (unsigned short*)(w + 12320768);         // 1.125 MB
  unsigned short* out2w = (unsigned short*)(w + 13500416);         // 48 or 12 MB
  unsigned short* xbf   = (unsigned short*)d_out;                      // 48 MB
  unsigned short* Vbuf  = (unsigned short*)((char*)d_out + 50331648);  // 48 MB

  const bool fullws = ws_size >= (size_t)13500416 + 50331648;

  // 1) fused convert(x->bf16) + mean-pool over P (q/k only need the mean)
  conv_mean<<<dim3(384), 256, 0, stream>>>(x, xbf, xm);

  // 2) weight convert+transpose (B^T bf16 layout)
  transpose_f32_bf16<<<dim3(96, 32), 256, 0, stream>>>(W_qkv, WqkvT, 1024, 3072, 3072);
  transpose_f32_bf16<<<dim3(32, 32), 256, 0, stream>>>(W_proj, WpT, 1024, 1024, 1024);

  // 3) qk = xm @ W_qkv[:, :2048] -> fp32 (small; plain mapping)
  gemm_bt<true, false><<<dim3(48), 256, 0, stream>>>(
      xm, WqkvT, qkbuf, nullptr, 384, 2048, 1024, 16);

  // 4) scores + softmax -> attn bf16
  softmax_k<<<dim3(64), 128, 0, stream>>>(qkbuf, attn);

  // 5) V = xbf @ W_qkv[:, 2048:3072] -> bf16 into d_out[48,96) (swizzled)
  gemm_bt<false, true><<<dim3(1536), 256, 0, stream>>>(
      xbf, WqkvT + (size_t)2048 * 1024, Vbuf, nullptr, 24576, 1024, 1024, 8);

  if (fullws) {
    // 6) attn-mix, all batches in one launch (64 bh x 32 col-tiles)
    attn_apply_mfma<<<dim3(2048), 256, 0, stream>>>(attn, Vbuf, out2w);
    // 7) out = out2 @ W_proj + b_proj -> fp32, one full-M launch
    gemm_bt<true, true><<<dim3(1536), 256, 0, stream>>>(
        out2w, WpT, out, b_proj, 24576, 1024, 1024, 8);
  } else {
    for (int b = 0; b < 4; ++b) {
      // per-batch: bh = h (b=0 inside kernel), pointers pre-offset
      attn_apply_mfma<<<dim3(512), 256, 0, stream>>>(
          attn + (size_t)b * 16 * 96 * 96,
          Vbuf + (size_t)b * 6144 * 1024,
          out2w);
      gemm_bt<true, true><<<dim3(384), 256, 0, stream>>>(
          out2w, WpT, out + (size_t)b * 6144 * 1024, b_proj, 6144, 1024, 1024, 8);
    }
  }
}

// Round 6
// 413.884 us; speedup vs baseline: 1.9048x; 1.1391x over previous
//
#include <hip/hip_runtime.h>
#include <cstdint>
#include <cstddef>

// VarAttention: B=4, N=96, P=64, C=1024, H=16, hd=64. tokens = 24576.
// Buffers are FP32 (reference dtype). Internal compute: bf16 MFMA, fp32 accum.
#define PPP  64
#define CC   1024

typedef __attribute__((ext_vector_type(8))) short short8;
typedef __attribute__((ext_vector_type(4))) float floatx4;
typedef __attribute__((ext_vector_type(4))) unsigned short ushort4v;

__device__ inline float bf2f(unsigned short u) {
  union { unsigned int i; float f; } v; v.i = ((unsigned int)u) << 16; return v.f;
}
__device__ inline unsigned short f2bf(float f) {
  union { float f; unsigned int i; } v; v.f = f;
  unsigned int x = v.i;
  unsigned int r = (x + 0x7fffu + ((x >> 16) & 1u)) >> 16;  // RNE
  return (unsigned short)r;
}

// global->LDS direct DMA, 16B/lane; LDS dest = wave-uniform base + lane*16.
#define GLD16(gp, lp)                                                          \
  __builtin_amdgcn_global_load_lds(                                            \
      (const __attribute__((address_space(1))) void*)(gp),                     \
      (__attribute__((address_space(3))) void*)(lp), 16, 0, 0)

// ---------------------------------------------------------------------------
// Fused convert + mean-pool: one pass over x (96 MB fp32).
//   xbf[bn*P+p][c] = bf16(x[...]);  xm[bn][c] = bf16(mean_p x)
// ---------------------------------------------------------------------------
__global__ __launch_bounds__(256) void conv_mean(
    const float* __restrict__ x, unsigned short* __restrict__ xbf,
    unsigned short* __restrict__ xm) {
  int bn = blockIdx.x;
  int c4 = threadIdx.x * 4;
  const float* xp = x + (size_t)bn * (PPP * CC) + c4;
  unsigned short* xo = xbf + (size_t)bn * (PPP * CC) + c4;
  float4 s = {0.f, 0.f, 0.f, 0.f};
#pragma unroll 8
  for (int p = 0; p < PPP; ++p) {
    float4 v = *(const float4*)&xp[(size_t)p * CC];
    s.x += v.x; s.y += v.y; s.z += v.z; s.w += v.w;
    ushort4v pk;
    pk.x = f2bf(v.x); pk.y = f2bf(v.y); pk.z = f2bf(v.z); pk.w = f2bf(v.w);
    *(ushort4v*)&xo[(size_t)p * CC] = pk;
  }
  ushort4v pm;
  pm.x = f2bf(s.x * (1.0f / PPP)); pm.y = f2bf(s.y * (1.0f / PPP));
  pm.z = f2bf(s.z * (1.0f / PPP)); pm.w = f2bf(s.w * (1.0f / PPP));
  *(ushort4v*)&xm[(size_t)bn * CC + c4] = pm;
}

// ---------------------------------------------------------------------------
// Convert+transpose: dst_bf16[c][r] = src_f32[r][c]. Grid (Cc/32, R/32), 256.
// ---------------------------------------------------------------------------
__global__ __launch_bounds__(256) void transpose_f32_bf16(
    const float* __restrict__ src, unsigned short* __restrict__ dst,
    int R, int Cc, int src_stride) {
  __shared__ unsigned short tile[32][33];
  int tc = blockIdx.x * 32, tr = blockIdx.y * 32;
  int tx = threadIdx.x & 31, ty = threadIdx.x >> 5;  // 32 x 8
  for (int yy = ty; yy < 32; yy += 8)
    tile[yy][tx] = f2bf(src[(size_t)(tr + yy) * src_stride + tc + tx]);
  __syncthreads();
  for (int yy = ty; yy < 32; yy += 8)
    dst[(size_t)(tc + yy) * R + tr + tx] = tile[tx][yy];
}

// ---------------------------------------------------------------------------
// MFMA bf16 GEMM: C[M][N] = A_bf16[M][K] @ BT_bf16[N][K]^T (+ fp32 bias).
// 128x128 tile, BK=32, 4 waves, 4x4 MFMA per wave; GLD16 staging (m97).
// SWIZ: XCD-aware mapping (requires nbx==8, grid%64==0) — each XCD (bid&7)
// owns a contiguous row-tile band for x8 A reuse in its private L2.
// Fragment layouts (m89/m91 verified): A[m=lane&15][k=quad*8+j];
// B[k][n=lane&15]; C/D col=lane&15, row=quad*4+reg.
// ---------------------------------------------------------------------------
template <bool F32OUT, bool SWIZ>
__global__ __launch_bounds__(256) void gemm_bt(
    const unsigned short* __restrict__ A, const unsigned short* __restrict__ BT,
    void* __restrict__ Cout, const float* __restrict__ bias,
    int M, int N, int K, int nbx) {
  __shared__ unsigned short As[128 * 32];
  __shared__ unsigned short Bs[128 * 32];

  int bx, by;
  {
    int bid = blockIdx.x;
    if (SWIZ) {
      bx = (bid >> 3) & 7;
      by = (bid & 7) * (gridDim.x >> 6) + (bid >> 6);
    } else {
      bx = bid % nbx;
      by = bid / nbx;
    }
  }
  const int rowBase = by * 128;
  const int colBase = bx * 128;
  const int t = threadIdx.x;
  const int wave = t >> 6, lane = t & 63;
  const int qr = wave >> 1, qc = wave & 1;
  const int m16 = lane & 15, quad = lane >> 4;

  floatx4 acc[4][4];
#pragma unroll
  for (int i = 0; i < 4; ++i)
#pragma unroll
    for (int j = 0; j < 4; ++j) {
      acc[i][j][0] = 0.f; acc[i][j][1] = 0.f; acc[i][j][2] = 0.f; acc[i][j][3] = 0.f;
    }

  for (int k0 = 0; k0 < K; k0 += 32) {
    __syncthreads();
#pragma unroll
    for (int u = 0; u < 2; ++u) {
      int ch = (u * 4 + wave) * 64 + lane;      // 0..511
      int row = ch >> 2, c8 = (ch & 3) << 3;    // 16B chunks of a 32-wide k-row
      GLD16(&A [(size_t)(rowBase + row) * K + k0 + c8], &As[ch * 8]);
      GLD16(&BT[(size_t)(colBase + row) * K + k0 + c8], &Bs[ch * 8]);
    }
    __syncthreads();

    short8 af[4], bfr[4];
#pragma unroll
    for (int i = 0; i < 4; ++i)
      af[i] = *(const short8*)&As[(qr * 64 + i * 16 + m16) * 32 + quad * 8];
#pragma unroll
    for (int j = 0; j < 4; ++j)
      bfr[j] = *(const short8*)&Bs[(qc * 64 + j * 16 + m16) * 32 + quad * 8];
#pragma unroll
    for (int i = 0; i < 4; ++i)
#pragma unroll
      for (int j = 0; j < 4; ++j)
        acc[i][j] = __builtin_amdgcn_mfma_f32_16x16x32_bf16(af[i], bfr[j], acc[i][j], 0, 0, 0);
  }

  float bv[4];
#pragma unroll
  for (int j = 0; j < 4; ++j)
    bv[j] = bias ? bias[colBase + qc * 64 + j * 16 + m16] : 0.f;

#pragma unroll
  for (int i = 0; i < 4; ++i) {
    int row0 = rowBase + qr * 64 + i * 16 + quad * 4;
#pragma unroll
    for (int j = 0; j < 4; ++j) {
      int col = colBase + qc * 64 + j * 16 + m16;
#pragma unroll
      for (int r = 0; r < 4; ++r) {
        float f = acc[i][j][r] + bv[j];
        if (F32OUT)
          ((float*)Cout)[(size_t)(row0 + r) * N + col] = f;
        else
          ((unsigned short*)Cout)[(size_t)(row0 + r) * N + col] = f2bf(f);
      }
    }
  }
}

// ---------------------------------------------------------------------------
// Per-(b,h) scores + softmax. qk (384 x 2048) fp32: [0,1024)=q, [1024,2048)=k.
// attn out: (B,H,96,96) bf16. Grid 64, block 128.
// R5 rewrite: q row in REGISTERS (no qs LDS, no 64-way conflict), ks[m][d]
// read is wave-broadcast (free), scores in LDS transposed sc[m][t] (per-lane
// stride 4B = conflict-free) instead of the scratch-spilled sc[96] array.
// ---------------------------------------------------------------------------
__global__ __launch_bounds__(128) void softmax_k(
    const float* __restrict__ qk, unsigned short* __restrict__ attn) {
  int bh = blockIdx.x;
  int b = bh >> 4, h = bh & 15;
  __shared__ float ks[96][64];   // 24 KB
  __shared__ float sc[96][96];   // 36 KB, [m][t] layout
  int t = threadIdx.x;
  for (int idx = t; idx < 96 * 64; idx += 128) {
    int n = idx >> 6, d = idx & 63;
    ks[n][d] = qk[(size_t)(b * 96 + n) * 2048 + 1024 + h * 64 + d];
  }
  __syncthreads();
  if (t < 96) {
    float qreg[64];
    const float* qrow = qk + (size_t)(b * 96 + t) * 2048 + h * 64;
#pragma unroll
    for (int d = 0; d < 64; ++d) qreg[d] = qrow[d];

    float mx = -1e30f;
    for (int m = 0; m < 96; ++m) {
      float s0 = 0.f, s1 = 0.f, s2 = 0.f, s3 = 0.f;
#pragma unroll
      for (int d = 0; d < 64; d += 4) {
        s0 += qreg[d + 0] * ks[m][d + 0];
        s1 += qreg[d + 1] * ks[m][d + 1];
        s2 += qreg[d + 2] * ks[m][d + 2];
        s3 += qreg[d + 3] * ks[m][d + 3];
      }
      float s = ((s0 + s1) + (s2 + s3)) * 0.125f;  // hd^-0.5
      sc[m][t] = s;
      mx = fmaxf(mx, s);
    }
    float sum = 0.f;
    for (int m = 0; m < 96; ++m) {
      float e = __expf(sc[m][t] - mx);
      sc[m][t] = e;
      sum += e;
    }
    float inv = 1.0f / sum;
    size_t base = (size_t)(bh * 96 + t) * 96;
    for (int m = 0; m < 96; ++m) attn[base + m] = f2bf(sc[m][t] * inv);
  }
}

// ---------------------------------------------------------------------------
// MFMA attn-apply (no LDS). Per (b,h): out2'(96 x 4096) = attn_bh(96x96) @
// V'_bh(96x4096), where V'[m][p*64+d] = V[((b*96+m)*64+p)*1024 + h*64+d].
// Grid = NBH*32 blocks (bh = bid>>5, 128-col tile ct = bid&31), 256 threads.
// ---------------------------------------------------------------------------
__global__ __launch_bounds__(256) void attn_apply_mfma(
    const unsigned short* __restrict__ attn, const unsigned short* __restrict__ V,
    unsigned short* __restrict__ out2) {
  const int bid = blockIdx.x;
  const int bh = bid >> 5, ct = bid & 31;
  const int b = bh >> 4;           // 0 when launched per-batch with grid 512
  const int t = threadIdx.x;
  const int wave = t >> 6, lane = t & 63;
  const int m16 = lane & 15, quad = lane >> 4;

  const unsigned short* An = attn + (size_t)bh * 96 * 96;   // attn[bh][n][m]
  const int vb = b * 96 * 64 * CC;                           // batch offset in V

  floatx4 acc[6][2];
#pragma unroll
  for (int i = 0; i < 6; ++i)
#pragma unroll
    for (int j = 0; j < 2; ++j) {
      acc[i][j][0] = 0.f; acc[i][j][1] = 0.f; acc[i][j][2] = 0.f; acc[i][j][3] = 0.f;
    }

  int p_[2], base_[2];
#pragma unroll
  for (int jj = 0; jj < 2; ++jj) {
    int colL = wave * 32 + jj * 16;              // 0..112, multiple of 16
    int p = ct * 2 + (colL >> 6);
    int d = (colL & 63) + m16;
    p_[jj] = p;
    base_[jj] = vb + p * CC + ((bh & 15) * 64) + d;   // + m*64*CC per k
  }

#pragma unroll
  for (int k0 = 0; k0 < 96; k0 += 32) {
    short8 af[6];
#pragma unroll
    for (int i = 0; i < 6; ++i)
      af[i] = *(const short8*)&An[(i * 16 + m16) * 96 + k0 + quad * 8];
#pragma unroll
    for (int jj = 0; jj < 2; ++jj) {
      short8 bfr;
#pragma unroll
      for (int j = 0; j < 8; ++j)
        bfr[j] = (short)V[(size_t)base_[jj] + (size_t)(k0 + quad * 8 + j) * (64 * CC)];
#pragma unroll
      for (int i = 0; i < 6; ++i)
        acc[i][jj] = __builtin_amdgcn_mfma_f32_16x16x32_bf16(af[i], bfr, acc[i][jj], 0, 0, 0);
    }
  }

#pragma unroll
  for (int jj = 0; jj < 2; ++jj) {
    int colL = wave * 32 + jj * 16;
    int d = (colL & 63) + m16;
    size_t obase = (size_t)(b * 96) * 64 * CC + (size_t)p_[jj] * CC + (bh & 15) * 64 + d;
#pragma unroll
    for (int i = 0; i < 6; ++i) {
#pragma unroll
      for (int r = 0; r < 4; ++r) {
        int n = i * 16 + quad * 4 + r;
        out2[obase + (size_t)n * (64 * CC)] = f2bf(acc[i][jj][r]);
      }
    }
  }
}

// ---------------------------------------------------------------------------
// Buffer plan (fp32 world):
//   d_out (96 MB fp32): [0,48) holds xbf (bf16 x) until the V-GEMM consumes
//   it; [48,96) holds V (bf16) until attn_apply consumes it. The final proj
//   GEMM then overwrites all of d_out with fp32 output.
//   Chunked fallback ordering proof: out chunk b writes [24b, 24(b+1)) MB.
//   Chunks 0,1 overwrite xbf (dead after V-GEMM). Chunk 2 writes [48,72) =
//   V[0],V[1] (dead after apply_0/1). Chunk 3 writes [72,96); apply_3 (reads
//   V[3] at [84,96)) precedes gemm_3 on the stream. Safe.
//   d_ws: WqkvT 6 | WpT 2 | xm .75 | qkbuf 3 | attn 1.125 | out2 (48 full /
//   12 chunked) MB.
// ---------------------------------------------------------------------------
extern "C" void kernel_launch(void* const* d_in, const int* in_sizes, int n_in,
                              void* d_out, int out_size, void* d_ws, size_t ws_size,
                              hipStream_t stream) {
  const float* x      = (const float*)d_in[0];  // (4,96,64,1024) fp32
  const float* W_qkv  = (const float*)d_in[1];  // (1024,3072) fp32
  const float* W_proj = (const float*)d_in[2];  // (1024,1024) fp32
  const float* b_proj = (const float*)d_in[3];  // (1024,) fp32
  float* out = (float*)d_out;                   // (4,96,64,1024) fp32

  char* w = (char*)d_ws;
  unsigned short* WqkvT = (unsigned short*)(w);                    // 6 MB
  unsigned short* WpT   = (unsigned short*)(w + 6291456);          // 2 MB
  unsigned short* xm    = (unsigned short*)(w + 8388608);          // 0.75 MB
  float*          qkbuf = (float*)(w + 9175040);                   // 3 MB
  unsigned short* attn  = (unsigned short*)(w + 12320768);         // 1.125 MB
  unsigned short* out2w = (unsigned short*)(w + 13500416);         // 48 or 12 MB
  unsigned short* xbf   = (unsigned short*)d_out;                      // 48 MB
  unsigned short* Vbuf  = (unsigned short*)((char*)d_out + 50331648);  // 48 MB

  const bool fullws = ws_size >= (size_t)13500416 + 50331648;

  // 1) fused convert(x->bf16) + mean-pool over P (q/k only need the mean)
  conv_mean<<<dim3(384), 256, 0, stream>>>(x, xbf, xm);

  // 2) weight convert+transpose (B^T bf16 layout)
  transpose_f32_bf16<<<dim3(96, 32), 256, 0, stream>>>(W_qkv, WqkvT, 1024, 3072, 3072);
  transpose_f32_bf16<<<dim3(32, 32), 256, 0, stream>>>(W_proj, WpT, 1024, 1024, 1024);

  // 3) qk = xm @ W_qkv[:, :2048] -> fp32 (small; plain mapping)
  gemm_bt<true, false><<<dim3(48), 256, 0, stream>>>(
      xm, WqkvT, qkbuf, nullptr, 384, 2048, 1024, 16);

  // 4) scores + softmax -> attn bf16
  softmax_k<<<dim3(64), 128, 0, stream>>>(qkbuf, attn);

  // 5) V = xbf @ W_qkv[:, 2048:3072] -> bf16 into d_out[48,96) (swizzled)
  gemm_bt<false, true><<<dim3(1536), 256, 0, stream>>>(
      xbf, WqkvT + (size_t)2048 * 1024, Vbuf, nullptr, 24576, 1024, 1024, 8);

  if (fullws) {
    // 6) attn-mix, all batches in one launch (64 bh x 32 col-tiles)
    attn_apply_mfma<<<dim3(2048), 256, 0, stream>>>(attn, Vbuf, out2w);
    // 7) out = out2 @ W_proj + b_proj -> fp32, one full-M launch
    gemm_bt<true, true><<<dim3(1536), 256, 0, stream>>>(
        out2w, WpT, out, b_proj, 24576, 1024, 1024, 8);
  } else {
    for (int b = 0; b < 4; ++b) {
      attn_apply_mfma<<<dim3(512), 256, 0, stream>>>(
          attn + (size_t)b * 16 * 96 * 96,
          Vbuf + (size_t)b * 6144 * 1024,
          out2w);
      gemm_bt<true, true><<<dim3(384), 256, 0, stream>>>(
          out2w, WpT, out + (size_t)b * 6144 * 1024, b_proj, 6144, 1024, 1024, 8);
    }
  }
}